// Round 12
// baseline (295.270 us; speedup 1.0000x reference)
//
#include <hip/hip_runtime.h>
#include <hip/hip_fp16.h>

#define H_IMG 256
#define W_IMG 512
#define NPIX  (H_IMG*W_IMG)   // 131072
#define BATCH 4
#define HID   64

#define TX 32
#define TY 8
#define HX (TX+2)   // 34
#define HY (TY+2)   // 10
#define HN (HX*HY)  // 340
#define LTH 512

// LDS: node-major, 64 halfs (128 B) per node, NO pad (global_load_lds writes
// linearly). Bank conflicts handled by XOR swizzle: chunk c8 of node n lives
// at halfs n*64 + ((c8 ^ (n&7))*8). Staging pre-swizzles the GLOBAL source
// chunk so the linear LDS write lands swizzled (rule: both-sides-or-neither).

typedef _Float16 half8 __attribute__((ext_vector_type(8)));
typedef float v4f __attribute__((ext_vector_type(4)));

#define GLOAD16(gp, lp) \
  __builtin_amdgcn_global_load_lds((const __attribute__((address_space(1))) unsigned int*)(gp), \
                                   (__attribute__((address_space(3))) unsigned int*)(lp), 16, 0, 0)

__device__ __forceinline__ float dinvf(int y, int x) {
  int cy = 3 - (y==0) - (y==(H_IMG-1));
  int cx = 3 - (x==0) - (x==(W_IMG-1));
  return rsqrtf((float)(cy*cx));
}

__device__ __forceinline__ unsigned pack2(float a, float b) {
  __half2 h = __floats2half2_rn(a, b);
  return *reinterpret_cast<unsigned*>(&h);
}

// WgT[l][f][k] = fp16(Wg[l][k][f])   (R2/R8-proven)
__global__ void k_wg(const float* __restrict__ Wg, __half* __restrict__ WgT) {
  int idx = blockIdx.x * 256 + threadIdx.x;          // 3*64*64 = 12288
  int l = idx >> 12, rem = idx & 4095;
  int f = rem >> 6, k = rem & 63;
  WgT[idx] = __float2half(Wg[(l << 12) + (k << 6) + f]);
}

// One GCN layer. MODE 0: build h0 from x on the fly; MODE 1: async-stage from hin.
// 512 threads: each handles 4 channel-octets of one node (half of R11's serial work).
template<int MODE>
__global__ __launch_bounds__(LTH, 6) void k_layer(
    const float* __restrict__ x,
    const float* __restrict__ W_in, const float* __restrict__ b_in,
    const __half* __restrict__ hin, const __half* __restrict__ wgt,
    const float* __restrict__ bg, __half* __restrict__ hout) {
  __shared__ __half hs[HN * 64];   // 43,520 B -> 3 blocks/CU (24 waves)
  const int tid = threadIdx.x;
  const int tx0 = blockIdx.x * TX;
  const int ty0 = blockIdx.y * TY;
  const int b   = blockIdx.z;

  const int l64 = tid & 63, lm = l64 & 15, lh = l64 >> 4, w = tid >> 6;

  // A fragments (WgT, fp16) + bias C-input (R8-proven)
  half8 af0[4], af1[4];
  v4f cb[4];
#pragma unroll
  for (int ft = 0; ft < 4; ++ft) {
    const __half* wp = wgt + (ft*16 + lm)*64 + lh*8;
    af0[ft] = *(const half8*)wp;
    af1[ft] = *(const half8*)(wp + 32);
    cb[ft] = *(const v4f*)(bg + ft*16 + (lh << 2));
  }

  // ---- staging ----
  if (MODE == 0) {
    // h0 halo built on the fly from x; swizzled ds-writes; OOB -> 0
    const float* xb = x + (size_t)b*3*NPIX;
    for (int n = tid; n < HN; n += LTH) {
      int row = n / HX, col = n - row*HX;
      int gy = ty0 - 1 + row, gx = tx0 - 1 + col;
      __half* hp = &hs[n << 6];
      const int s7 = n & 7;
      if ((unsigned)gy < H_IMG && (unsigned)gx < W_IMG) {
        int gi = (gy << 9) + gx;
        float x0 = xb[gi], x1 = xb[NPIX+gi], x2 = xb[2*NPIX+gi];
#pragma unroll
        for (int c8 = 0; c8 < 8; ++c8) {
          float rr[8];
#pragma unroll
          for (int k = 0; k < 8; ++k) {
            int f = (c8 << 3) + k;
            rr[k] = fmaf(x0, W_in[f], fmaf(x1, W_in[64+f], fmaf(x2, W_in[128+f], b_in[f])));
          }
          uint4 u = make_uint4(pack2(rr[0],rr[1]), pack2(rr[2],rr[3]),
                               pack2(rr[4],rr[5]), pack2(rr[6],rr[7]));
          *(uint4*)(hp + ((c8 ^ s7) << 3)) = u;
        }
      } else {
        uint4 z = make_uint4(0u,0u,0u,0u);
#pragma unroll
        for (int c8 = 0; c8 < 8; ++c8)
          *(uint4*)(hp + ((c8 ^ s7) << 3)) = z;
      }
    }
  } else {
    // async staging: back-to-back global_load_lds (16B); clamped addrs,
    // OOB handled by zeroed stencil scales. (R11-proven)
    const __half* hb = hin + (size_t)b * NPIX * HID;
    for (int it = tid; it < HN*8; it += LTH) {
      int nl = it >> 3;
      int c8s = (it & 7) ^ (nl & 7);
      int row = nl / HX, col = nl - row*HX;
      int sy = ty0 - 1 + row, sx = tx0 - 1 + col;
      sy = max(0, min(H_IMG-1, sy));
      sx = max(0, min(W_IMG-1, sx));
      const __half* gp = hb + ((size_t)((sy << 9) + sx)) * 64 + (c8s << 3);
      GLOAD16(gp, &hs[it << 3]);
    }
  }
  __syncthreads();   // compiler drains vmcnt before barrier

  // ---- 9-point stencil, fp32 acc; 4 octets/thread (c4 selects half) ----
  const int nn0 = tid & 255;          // node: row nn0>>5, col nn0&31
  const int c4  = tid >> 8;           // 0 or 1: octets c4*4 .. c4*4+3
  const int lx = nn0 & 31, ly = nn0 >> 5;
  const int gy = ty0 + ly, gx = tx0 + lx;
  const float dc = dinvf(gy, gx);
  float sc[9];
  int   nbn[9];
#pragma unroll
  for (int r = 0; r < 3; ++r)
#pragma unroll
    for (int c = 0; c < 3; ++c) {
      int ny = gy - 1 + r, nx = gx - 1 + c;
      bool ok = ((unsigned)ny < H_IMG) && ((unsigned)nx < W_IMG);
      sc[r*3+c] = ok ? dc * dinvf(ny, nx) : 0.f;
      nbn[r*3+c] = (ly + r)*HX + lx + c;   // node index in halo
    }
  half8 sreg[4];
#pragma unroll
  for (int ch4 = 0; ch4 < 4; ++ch4) {
    const int ch = (c4 << 2) + ch4;
    float acc[8] = {0.f,0.f,0.f,0.f,0.f,0.f,0.f,0.f};
#pragma unroll
    for (int j = 0; j < 9; ++j) {
      int nj = nbn[j];
      half8 v = *(const half8*)&hs[(nj << 6) + (((ch ^ (nj & 7))) << 3)];
      float s = sc[j];
#pragma unroll
      for (int k = 0; k < 8; ++k) acc[k] = fmaf(s, (float)v[k], acc[k]);
    }
    half8 o;
#pragma unroll
    for (int k = 0; k < 8; ++k) o[k] = (_Float16)acc[k];
    sreg[ch4] = o;
  }
  __syncthreads();                 // all halo reads done; safe to overwrite

  // spill s (fp16) into LDS, node nn0, swizzled chunks
  {
    __half* hp = &hs[nn0 << 6];
    const int s7 = nn0 & 7;
#pragma unroll
    for (int ch4 = 0; ch4 < 4; ++ch4) {
      const int ch = (c4 << 2) + ch4;
      *(half8*)(hp + ((ch ^ s7) << 3)) = sreg[ch4];
    }
  }
  __syncthreads();

  // ---- GEMM: D = WgT (64f x 64k) x s^T; 8 waves x 2 node-groups ----
  __half* ho = hout + (size_t)b * NPIX * HID;
#pragma unroll
  for (int i = 0; i < 2; ++i) {
    int g  = (w << 1) + i;          // node group: 16 nodes (16 groups total)
    int nn = (g << 4) + lm;         // local node for this lane
    const int s7 = nn & 7;
    const __half* np = &hs[nn << 6];
    half8 b0 = *(const half8*)(np + ((lh ^ s7) << 3));
    half8 b1 = *(const half8*)(np + (((lh + 4) ^ s7) << 3));
    v4f d[4];
#pragma unroll
    for (int ft = 0; ft < 4; ++ft) {
      v4f t = __builtin_amdgcn_mfma_f32_16x16x32_f16(af0[ft], b0, cb[ft], 0, 0, 0);
      d[ft]  = __builtin_amdgcn_mfma_f32_16x16x32_f16(af1[ft], b1, t,     0, 0, 0);
    }
    // lane holds features ft*16 + lh*4 + r of node nn; node nn: row nn>>5, col nn&31
    __half* hp = ho + (size_t)(((ty0 + (nn >> 5)) << 9) + tx0 + (nn & 31)) * HID + (lh << 2);
#pragma unroll
    for (int ft = 0; ft < 4; ++ft) {
      uint2 u;
      u.x = pack2(fmaxf(d[ft][0], 0.f), fmaxf(d[ft][1], 0.f));
      u.y = pack2(fmaxf(d[ft][2], 0.f), fmaxf(d[ft][3], 0.f));
      *(uint2*)(hp + ft*16) = u;
    }
  }
}

// out[b,c,n] = h[b,n,:] @ W_out + b_out   (R2/R8-proven)
__global__ void k_out(const __half* __restrict__ h, const float* __restrict__ W_out,
                      const float* __restrict__ b_out, float* __restrict__ out) {
  int idx = blockIdx.x * 256 + threadIdx.x;
  int c8 = idx & 7;
  int bn = idx >> 3;
  uint4 raw = *reinterpret_cast<const uint4*>(h + (size_t)bn*64 + (size_t)c8*8);
  const __half2* hp = reinterpret_cast<const __half2*>(&raw);
  float p0 = 0.f, p1 = 0.f, p2 = 0.f;
  int fbase = c8*8;
#pragma unroll
  for (int j = 0; j < 4; ++j) {
    float2 f = __half22float2(hp[j]);
    const float* wv = &W_out[(fbase + j*2)*3];
    p0 += f.x*wv[0] + f.y*wv[3];
    p1 += f.x*wv[1] + f.y*wv[4];
    p2 += f.x*wv[2] + f.y*wv[5];
  }
#pragma unroll
  for (int m = 1; m < 8; m <<= 1) {
    p0 += __shfl_xor(p0, m);
    p1 += __shfl_xor(p1, m);
    p2 += __shfl_xor(p2, m);
  }
  if (c8 == 0) {
    int b = bn >> 17, n = bn & (NPIX-1);
    out[((size_t)b*3 + 0)*NPIX + n] = p0 + b_out[0];
    out[((size_t)b*3 + 1)*NPIX + n] = p1 + b_out[1];
    out[((size_t)b*3 + 2)*NPIX + n] = p2 + b_out[2];
  }
}

extern "C" void kernel_launch(void* const* d_in, const int* in_sizes, int n_in,
                              void* d_out, int out_size, void* d_ws, size_t ws_size,
                              hipStream_t stream) {
  const float* x     = (const float*)d_in[0];
  // d_in[1] = src, d_in[2] = dst — unused: grid topology is analytic
  const float* W_in  = (const float*)d_in[3];
  const float* b_in  = (const float*)d_in[4];
  const float* Wg    = (const float*)d_in[5];
  const float* bg    = (const float*)d_in[6];
  const float* W_out = (const float*)d_in[7];
  const float* b_out = (const float*)d_in[8];
  float* out = (float*)d_out;

  // WgT fp16 scratch at head of d_out (R2/R8-proven: k_out fully overwrites later)
  __half* WgT = (__half*)d_out;
  __half* hA = (__half*)d_ws;
  __half* hB = hA + (size_t)BATCH*NPIX*HID;

  k_wg<<<dim3(48), 256, 0, stream>>>(Wg, WgT);

  dim3 lg(W_IMG/TX, H_IMG/TY, BATCH);   // 16 x 32 x 4
  k_layer<0><<<lg, LTH, 0, stream>>>(x, W_in, b_in, nullptr, WgT,        bg,       hA);
  k_layer<1><<<lg, LTH, 0, stream>>>(nullptr, nullptr, nullptr, hA, WgT + 4096, bg + 64,  hB);
  k_layer<1><<<lg, LTH, 0, stream>>>(nullptr, nullptr, nullptr, hB, WgT + 8192, bg + 128, hA);

  k_out<<<dim3(BATCH*NPIX*8/256), 256, 0, stream>>>(hA, W_out, b_out, out);
}

// Round 13
// 203.837 us; speedup vs baseline: 1.4486x; 1.4486x over previous
//
#include <hip/hip_runtime.h>
#include <hip/hip_fp16.h>

#define H_IMG 256
#define W_IMG 512
#define NPIX  (H_IMG*W_IMG)   // 131072
#define BATCH 4
#define HID   64

#define TX 32
#define TY 8
#define HX (TX+2)   // 34
#define HY (TY+2)   // 10
#define HN (HX*HY)  // 340
#define LTH 512

// LDS: node-major, 64 halfs (128 B) per node, NO pad (global_load_lds writes
// linearly). Bank conflicts handled by XOR swizzle: chunk c8 of node n lives
// at halfs n*64 + ((c8 ^ (n&7))*8). Staging pre-swizzles the GLOBAL source
// chunk so the linear LDS write lands swizzled (rule: both-sides-or-neither).

typedef _Float16 half8 __attribute__((ext_vector_type(8)));
typedef float v4f __attribute__((ext_vector_type(4)));

#define GLOAD16(gp, lp) \
  __builtin_amdgcn_global_load_lds((const __attribute__((address_space(1))) unsigned int*)(gp), \
                                   (__attribute__((address_space(3))) unsigned int*)(lp), 16, 0, 0)

__device__ __forceinline__ float dinvf(int y, int x) {
  int cy = 3 - (y==0) - (y==(H_IMG-1));
  int cx = 3 - (x==0) - (x==(W_IMG-1));
  return rsqrtf((float)(cy*cx));
}

__device__ __forceinline__ unsigned pack2(float a, float b) {
  __half2 h = __floats2half2_rn(a, b);
  return *reinterpret_cast<unsigned*>(&h);
}

// WgT[l][f][k] = fp16(Wg[l][k][f])   (R2/R8-proven)
__global__ void k_wg(const float* __restrict__ Wg, __half* __restrict__ WgT) {
  int idx = blockIdx.x * 256 + threadIdx.x;          // 3*64*64 = 12288
  int l = idx >> 12, rem = idx & 4095;
  int f = rem >> 6, k = rem & 63;
  WgT[idx] = __float2half(Wg[(l << 12) + (k << 6) + f]);
}

// One GCN layer. MODE 0: build h0 from x on the fly; MODE 1: async-stage from hin.
// 512 threads, 4 octets/thread. __launch_bounds__(512,2): 2 waves/EU min ->
// VGPR ceiling 256 (actual ~76, NO spill; R12's (512,6) forced 40 VGPR + spills).
// Occupancy: 2 blocks/CU x 8 waves = 16 waves/CU (VGPR>64 caps 4 waves/SIMD).
template<int MODE>
__global__ __launch_bounds__(LTH, 2) void k_layer(
    const float* __restrict__ x,
    const float* __restrict__ W_in, const float* __restrict__ b_in,
    const __half* __restrict__ hin, const __half* __restrict__ wgt,
    const float* __restrict__ bg, __half* __restrict__ hout) {
  __shared__ __half hs[HN * 64];   // 43,520 B
  const int tid = threadIdx.x;
  const int tx0 = blockIdx.x * TX;
  const int ty0 = blockIdx.y * TY;
  const int b   = blockIdx.z;

  const int l64 = tid & 63, lm = l64 & 15, lh = l64 >> 4, w = tid >> 6;

  // A fragments (WgT, fp16) + bias C-input (R8-proven)
  half8 af0[4], af1[4];
  v4f cb[4];
#pragma unroll
  for (int ft = 0; ft < 4; ++ft) {
    const __half* wp = wgt + (ft*16 + lm)*64 + lh*8;
    af0[ft] = *(const half8*)wp;
    af1[ft] = *(const half8*)(wp + 32);
    cb[ft] = *(const v4f*)(bg + ft*16 + (lh << 2));
  }

  // ---- staging ----
  if (MODE == 0) {
    // h0 halo built on the fly from x; swizzled ds-writes; OOB -> 0
    const float* xb = x + (size_t)b*3*NPIX;
    for (int n = tid; n < HN; n += LTH) {
      int row = n / HX, col = n - row*HX;
      int gy = ty0 - 1 + row, gx = tx0 - 1 + col;
      __half* hp = &hs[n << 6];
      const int s7 = n & 7;
      if ((unsigned)gy < H_IMG && (unsigned)gx < W_IMG) {
        int gi = (gy << 9) + gx;
        float x0 = xb[gi], x1 = xb[NPIX+gi], x2 = xb[2*NPIX+gi];
#pragma unroll
        for (int c8 = 0; c8 < 8; ++c8) {
          float rr[8];
#pragma unroll
          for (int k = 0; k < 8; ++k) {
            int f = (c8 << 3) + k;
            rr[k] = fmaf(x0, W_in[f], fmaf(x1, W_in[64+f], fmaf(x2, W_in[128+f], b_in[f])));
          }
          uint4 u = make_uint4(pack2(rr[0],rr[1]), pack2(rr[2],rr[3]),
                               pack2(rr[4],rr[5]), pack2(rr[6],rr[7]));
          *(uint4*)(hp + ((c8 ^ s7) << 3)) = u;
        }
      } else {
        uint4 z = make_uint4(0u,0u,0u,0u);
#pragma unroll
        for (int c8 = 0; c8 < 8; ++c8)
          *(uint4*)(hp + ((c8 ^ s7) << 3)) = z;
      }
    }
  } else {
    // async staging: back-to-back global_load_lds (16B); clamped addrs,
    // OOB handled by zeroed stencil scales. (R11-proven)
    const __half* hb = hin + (size_t)b * NPIX * HID;
    for (int it = tid; it < HN*8; it += LTH) {
      int nl = it >> 3;
      int c8s = (it & 7) ^ (nl & 7);
      int row = nl / HX, col = nl - row*HX;
      int sy = ty0 - 1 + row, sx = tx0 - 1 + col;
      sy = max(0, min(H_IMG-1, sy));
      sx = max(0, min(W_IMG-1, sx));
      const __half* gp = hb + ((size_t)((sy << 9) + sx)) * 64 + (c8s << 3);
      GLOAD16(gp, &hs[it << 3]);
    }
  }
  __syncthreads();   // compiler drains vmcnt before barrier

  // ---- 9-point stencil, fp32 acc; 4 octets/thread (c4 selects half) ----
  const int nn0 = tid & 255;          // node: row nn0>>5, col nn0&31
  const int c4  = tid >> 8;           // 0 or 1: octets c4*4 .. c4*4+3
  const int lx = nn0 & 31, ly = nn0 >> 5;
  const int gy = ty0 + ly, gx = tx0 + lx;
  const float dc = dinvf(gy, gx);
  float sc[9];
  int   nbn[9];
#pragma unroll
  for (int r = 0; r < 3; ++r)
#pragma unroll
    for (int c = 0; c < 3; ++c) {
      int ny = gy - 1 + r, nx = gx - 1 + c;
      bool ok = ((unsigned)ny < H_IMG) && ((unsigned)nx < W_IMG);
      sc[r*3+c] = ok ? dc * dinvf(ny, nx) : 0.f;
      nbn[r*3+c] = (ly + r)*HX + lx + c;   // node index in halo
    }
  half8 sreg[4];
#pragma unroll
  for (int ch4 = 0; ch4 < 4; ++ch4) {
    const int ch = (c4 << 2) + ch4;
    float acc[8] = {0.f,0.f,0.f,0.f,0.f,0.f,0.f,0.f};
#pragma unroll
    for (int j = 0; j < 9; ++j) {
      int nj = nbn[j];
      half8 v = *(const half8*)&hs[(nj << 6) + (((ch ^ (nj & 7))) << 3)];
      float s = sc[j];
#pragma unroll
      for (int k = 0; k < 8; ++k) acc[k] = fmaf(s, (float)v[k], acc[k]);
    }
    half8 o;
#pragma unroll
    for (int k = 0; k < 8; ++k) o[k] = (_Float16)acc[k];
    sreg[ch4] = o;
  }
  __syncthreads();                 // all halo reads done; safe to overwrite

  // spill s (fp16) into LDS, node nn0, swizzled chunks
  {
    __half* hp = &hs[nn0 << 6];
    const int s7 = nn0 & 7;
#pragma unroll
    for (int ch4 = 0; ch4 < 4; ++ch4) {
      const int ch = (c4 << 2) + ch4;
      *(half8*)(hp + ((ch ^ s7) << 3)) = sreg[ch4];
    }
  }
  __syncthreads();

  // ---- GEMM: D = WgT (64f x 64k) x s^T; 8 waves x 2 node-groups ----
  __half* ho = hout + (size_t)b * NPIX * HID;
#pragma unroll
  for (int i = 0; i < 2; ++i) {
    int g  = (w << 1) + i;          // node group: 16 nodes (16 groups total)
    int nn = (g << 4) + lm;         // local node for this lane
    const int s7 = nn & 7;
    const __half* np = &hs[nn << 6];
    half8 b0 = *(const half8*)(np + ((lh ^ s7) << 3));
    half8 b1 = *(const half8*)(np + (((lh + 4) ^ s7) << 3));
    v4f d[4];
#pragma unroll
    for (int ft = 0; ft < 4; ++ft) {
      v4f t = __builtin_amdgcn_mfma_f32_16x16x32_f16(af0[ft], b0, cb[ft], 0, 0, 0);
      d[ft]  = __builtin_amdgcn_mfma_f32_16x16x32_f16(af1[ft], b1, t,     0, 0, 0);
    }
    // lane holds features ft*16 + lh*4 + r of node nn; node nn: row nn>>5, col nn&31
    __half* hp = ho + (size_t)(((ty0 + (nn >> 5)) << 9) + tx0 + (nn & 31)) * HID + (lh << 2);
#pragma unroll
    for (int ft = 0; ft < 4; ++ft) {
      uint2 u;
      u.x = pack2(fmaxf(d[ft][0], 0.f), fmaxf(d[ft][1], 0.f));
      u.y = pack2(fmaxf(d[ft][2], 0.f), fmaxf(d[ft][3], 0.f));
      *(uint2*)(hp + ft*16) = u;
    }
  }
}

// out[b,c,n] = h[b,n,:] @ W_out + b_out   (R2/R8-proven)
__global__ void k_out(const __half* __restrict__ h, const float* __restrict__ W_out,
                      const float* __restrict__ b_out, float* __restrict__ out) {
  int idx = blockIdx.x * 256 + threadIdx.x;
  int c8 = idx & 7;
  int bn = idx >> 3;
  uint4 raw = *reinterpret_cast<const uint4*>(h + (size_t)bn*64 + (size_t)c8*8);
  const __half2* hp = reinterpret_cast<const __half2*>(&raw);
  float p0 = 0.f, p1 = 0.f, p2 = 0.f;
  int fbase = c8*8;
#pragma unroll
  for (int j = 0; j < 4; ++j) {
    float2 f = __half22float2(hp[j]);
    const float* wv = &W_out[(fbase + j*2)*3];
    p0 += f.x*wv[0] + f.y*wv[3];
    p1 += f.x*wv[1] + f.y*wv[4];
    p2 += f.x*wv[2] + f.y*wv[5];
  }
#pragma unroll
  for (int m = 1; m < 8; m <<= 1) {
    p0 += __shfl_xor(p0, m);
    p1 += __shfl_xor(p1, m);
    p2 += __shfl_xor(p2, m);
  }
  if (c8 == 0) {
    int b = bn >> 17, n = bn & (NPIX-1);
    out[((size_t)b*3 + 0)*NPIX + n] = p0 + b_out[0];
    out[((size_t)b*3 + 1)*NPIX + n] = p1 + b_out[1];
    out[((size_t)b*3 + 2)*NPIX + n] = p2 + b_out[2];
  }
}

extern "C" void kernel_launch(void* const* d_in, const int* in_sizes, int n_in,
                              void* d_out, int out_size, void* d_ws, size_t ws_size,
                              hipStream_t stream) {
  const float* x     = (const float*)d_in[0];
  // d_in[1] = src, d_in[2] = dst — unused: grid topology is analytic
  const float* W_in  = (const float*)d_in[3];
  const float* b_in  = (const float*)d_in[4];
  const float* Wg    = (const float*)d_in[5];
  const float* bg    = (const float*)d_in[6];
  const float* W_out = (const float*)d_in[7];
  const float* b_out = (const float*)d_in[8];
  float* out = (float*)d_out;

  // WgT fp16 scratch at head of d_out (R2/R8-proven: k_out fully overwrites later)
  __half* WgT = (__half*)d_out;
  __half* hA = (__half*)d_ws;
  __half* hB = hA + (size_t)BATCH*NPIX*HID;

  k_wg<<<dim3(48), 256, 0, stream>>>(Wg, WgT);

  dim3 lg(W_IMG/TX, H_IMG/TY, BATCH);   // 16 x 32 x 4
  k_layer<0><<<lg, LTH, 0, stream>>>(x, W_in, b_in, nullptr, WgT,        bg,       hA);
  k_layer<1><<<lg, LTH, 0, stream>>>(nullptr, nullptr, nullptr, hA, WgT + 4096, bg + 64,  hB);
  k_layer<1><<<lg, LTH, 0, stream>>>(nullptr, nullptr, nullptr, hB, WgT + 8192, bg + 128, hA);

  k_out<<<dim3(BATCH*NPIX*8/256), 256, 0, stream>>>(hA, W_out, b_out, out);
}

// Round 14
// 150.376 us; speedup vs baseline: 1.9635x; 1.3555x over previous
//
#include <hip/hip_runtime.h>
#include <hip/hip_fp16.h>

#define H_IMG 256
#define W_IMG 512
#define NPIX  (H_IMG*W_IMG)   // 131072
#define BATCH 4
#define HID   64

#define TX 16
#define TY 8
#define HX (TX+2)   // 18
#define HY (TY+2)   // 10
#define HN (HX*HY)  // 180
#define TN (TX*TY)  // 128 output nodes
#define LTH 256

// LDS: node-major, 64 halfs (128 B) per node, NO pad (global_load_lds writes
// linearly). Bank conflicts handled by XOR swizzle: chunk c8 of node n lives
// at halfs n*64 + ((c8 ^ (n&7))*8). Staging pre-swizzles the GLOBAL source
// chunk so the linear LDS write lands swizzled (rule: both-sides-or-neither).

typedef _Float16 half8 __attribute__((ext_vector_type(8)));
typedef float v4f __attribute__((ext_vector_type(4)));

#define GLOAD16(gp, lp) \
  __builtin_amdgcn_global_load_lds((const __attribute__((address_space(1))) unsigned int*)(gp), \
                                   (__attribute__((address_space(3))) unsigned int*)(lp), 16, 0, 0)

__device__ __forceinline__ float dinvf(int y, int x) {
  int cy = 3 - (y==0) - (y==(H_IMG-1));
  int cx = 3 - (x==0) - (x==(W_IMG-1));
  return rsqrtf((float)(cy*cx));
}

__device__ __forceinline__ unsigned pack2(float a, float b) {
  __half2 h = __floats2half2_rn(a, b);
  return *reinterpret_cast<unsigned*>(&h);
}

// WgT[l][f][k] = fp16(Wg[l][k][f])   (R2/R8-proven)
__global__ void k_wg(const float* __restrict__ Wg, __half* __restrict__ WgT) {
  int idx = blockIdx.x * 256 + threadIdx.x;          // 3*64*64 = 12288
  int l = idx >> 12, rem = idx & 4095;
  int f = rem >> 6, k = rem & 63;
  WgT[idx] = __float2half(Wg[(l << 12) + (k << 6) + f]);
}

// One GCN layer. MODE 0: build h0 from x on the fly; MODE 1: async-stage from hin.
// 16x8 tile, 256 threads, 4 octets/thread: 23 KB LDS -> up to 6 blocks/CU
// (24 waves/CU, 2x R11's latency hiding at R11's proven block shape).
template<int MODE>
__global__ __launch_bounds__(LTH, 4) void k_layer(
    const float* __restrict__ x,
    const float* __restrict__ W_in, const float* __restrict__ b_in,
    const __half* __restrict__ hin, const __half* __restrict__ wgt,
    const float* __restrict__ bg, __half* __restrict__ hout) {
  __shared__ __half hs[HN * 64];   // 23,040 B
  const int tid = threadIdx.x;
  const int tx0 = blockIdx.x * TX;
  const int ty0 = blockIdx.y * TY;
  const int b   = blockIdx.z;

  const int l64 = tid & 63, lm = l64 & 15, lh = l64 >> 4, w = tid >> 6;

  // A fragments (WgT, fp16) + bias C-input (R8-proven)
  half8 af0[4], af1[4];
  v4f cb[4];
#pragma unroll
  for (int ft = 0; ft < 4; ++ft) {
    const __half* wp = wgt + (ft*16 + lm)*64 + lh*8;
    af0[ft] = *(const half8*)wp;
    af1[ft] = *(const half8*)(wp + 32);
    cb[ft] = *(const v4f*)(bg + ft*16 + (lh << 2));
  }

  // ---- staging ----
  if (MODE == 0) {
    // h0 halo built on the fly from x; swizzled ds-writes; OOB -> 0
    const float* xb = x + (size_t)b*3*NPIX;
    for (int n = tid; n < HN; n += LTH) {
      int row = n / HX, col = n - row*HX;
      int gy = ty0 - 1 + row, gx = tx0 - 1 + col;
      __half* hp = &hs[n << 6];
      const int s7 = n & 7;
      if ((unsigned)gy < H_IMG && (unsigned)gx < W_IMG) {
        int gi = (gy << 9) + gx;
        float x0 = xb[gi], x1 = xb[NPIX+gi], x2 = xb[2*NPIX+gi];
#pragma unroll
        for (int c8 = 0; c8 < 8; ++c8) {
          float rr[8];
#pragma unroll
          for (int k = 0; k < 8; ++k) {
            int f = (c8 << 3) + k;
            rr[k] = fmaf(x0, W_in[f], fmaf(x1, W_in[64+f], fmaf(x2, W_in[128+f], b_in[f])));
          }
          uint4 u = make_uint4(pack2(rr[0],rr[1]), pack2(rr[2],rr[3]),
                               pack2(rr[4],rr[5]), pack2(rr[6],rr[7]));
          *(uint4*)(hp + ((c8 ^ s7) << 3)) = u;
        }
      } else {
        uint4 z = make_uint4(0u,0u,0u,0u);
#pragma unroll
        for (int c8 = 0; c8 < 8; ++c8)
          *(uint4*)(hp + ((c8 ^ s7) << 3)) = z;
      }
    }
  } else {
    // async staging: back-to-back global_load_lds (16B); clamped addrs,
    // OOB handled by zeroed stencil scales. (R11-proven)
    const __half* hb = hin + (size_t)b * NPIX * HID;
    for (int it = tid; it < HN*8; it += LTH) {
      int nl = it >> 3;
      int c8s = (it & 7) ^ (nl & 7);
      int row = nl / HX, col = nl - row*HX;
      int sy = ty0 - 1 + row, sx = tx0 - 1 + col;
      sy = max(0, min(H_IMG-1, sy));
      sx = max(0, min(W_IMG-1, sx));
      const __half* gp = hb + ((size_t)((sy << 9) + sx)) * 64 + (c8s << 3);
      GLOAD16(gp, &hs[it << 3]);
    }
  }
  __syncthreads();   // compiler drains vmcnt before barrier

  // ---- 9-point stencil, fp32 acc; 2 threads/node x 4 octets (c4 half) ----
  const int nn0 = tid & (TN-1);       // node: row nn0>>4, col nn0&15
  const int c4  = tid >> 7;           // 0 or 1: octets c4*4 .. c4*4+3
  const int lx = nn0 & 15, ly = nn0 >> 4;
  const int gy = ty0 + ly, gx = tx0 + lx;
  const float dc = dinvf(gy, gx);
  float sc[9];
  int   nbn[9];
#pragma unroll
  for (int r = 0; r < 3; ++r)
#pragma unroll
    for (int c = 0; c < 3; ++c) {
      int ny = gy - 1 + r, nx = gx - 1 + c;
      bool ok = ((unsigned)ny < H_IMG) && ((unsigned)nx < W_IMG);
      sc[r*3+c] = ok ? dc * dinvf(ny, nx) : 0.f;
      nbn[r*3+c] = (ly + r)*HX + lx + c;   // node index in halo
    }
  half8 sreg[4];
#pragma unroll
  for (int ch4 = 0; ch4 < 4; ++ch4) {
    const int ch = (c4 << 2) + ch4;
    float acc[8] = {0.f,0.f,0.f,0.f,0.f,0.f,0.f,0.f};
#pragma unroll
    for (int j = 0; j < 9; ++j) {
      int nj = nbn[j];
      half8 v = *(const half8*)&hs[(nj << 6) + (((ch ^ (nj & 7))) << 3)];
      float s = sc[j];
#pragma unroll
      for (int k = 0; k < 8; ++k) acc[k] = fmaf(s, (float)v[k], acc[k]);
    }
    half8 o;
#pragma unroll
    for (int k = 0; k < 8; ++k) o[k] = (_Float16)acc[k];
    sreg[ch4] = o;
  }
  __syncthreads();                 // all halo reads done; safe to overwrite

  // spill s (fp16) into LDS, node nn0, swizzled chunks
  {
    __half* hp = &hs[nn0 << 6];
    const int s7 = nn0 & 7;
#pragma unroll
    for (int ch4 = 0; ch4 < 4; ++ch4) {
      const int ch = (c4 << 2) + ch4;
      *(half8*)(hp + ((ch ^ s7) << 3)) = sreg[ch4];
    }
  }
  __syncthreads();

  // ---- GEMM: D = WgT (64f x 64k) x s^T; 4 waves x 2 node-groups ----
  __half* ho = hout + (size_t)b * NPIX * HID;
#pragma unroll
  for (int i = 0; i < 2; ++i) {
    int g  = (w << 1) + i;          // node group: 16 nodes (8 groups total)
    int nn = (g << 4) + lm;         // local node for this lane
    const int s7 = nn & 7;
    const __half* np = &hs[nn << 6];
    half8 b0 = *(const half8*)(np + ((lh ^ s7) << 3));
    half8 b1 = *(const half8*)(np + (((lh + 4) ^ s7) << 3));
    v4f d[4];
#pragma unroll
    for (int ft = 0; ft < 4; ++ft) {
      v4f t = __builtin_amdgcn_mfma_f32_16x16x32_f16(af0[ft], b0, cb[ft], 0, 0, 0);
      d[ft]  = __builtin_amdgcn_mfma_f32_16x16x32_f16(af1[ft], b1, t,     0, 0, 0);
    }
    // lane holds features ft*16 + lh*4 + r of node nn; node nn: row nn>>4, col nn&15
    __half* hp = ho + (size_t)(((ty0 + (nn >> 4)) << 9) + tx0 + (nn & 15)) * HID + (lh << 2);
#pragma unroll
    for (int ft = 0; ft < 4; ++ft) {
      uint2 u;
      u.x = pack2(fmaxf(d[ft][0], 0.f), fmaxf(d[ft][1], 0.f));
      u.y = pack2(fmaxf(d[ft][2], 0.f), fmaxf(d[ft][3], 0.f));
      *(uint2*)(hp + ft*16) = u;
    }
  }
}

// out[b,c,n] = h[b,n,:] @ W_out + b_out   (R2/R8-proven)
__global__ void k_out(const __half* __restrict__ h, const float* __restrict__ W_out,
                      const float* __restrict__ b_out, float* __restrict__ out) {
  int idx = blockIdx.x * 256 + threadIdx.x;
  int c8 = idx & 7;
  int bn = idx >> 3;
  uint4 raw = *reinterpret_cast<const uint4*>(h + (size_t)bn*64 + (size_t)c8*8);
  const __half2* hp = reinterpret_cast<const __half2*>(&raw);
  float p0 = 0.f, p1 = 0.f, p2 = 0.f;
  int fbase = c8*8;
#pragma unroll
  for (int j = 0; j < 4; ++j) {
    float2 f = __half22float2(hp[j]);
    const float* wv = &W_out[(fbase + j*2)*3];
    p0 += f.x*wv[0] + f.y*wv[3];
    p1 += f.x*wv[1] + f.y*wv[4];
    p2 += f.x*wv[2] + f.y*wv[5];
  }
#pragma unroll
  for (int m = 1; m < 8; m <<= 1) {
    p0 += __shfl_xor(p0, m);
    p1 += __shfl_xor(p1, m);
    p2 += __shfl_xor(p2, m);
  }
  if (c8 == 0) {
    int b = bn >> 17, n = bn & (NPIX-1);
    out[((size_t)b*3 + 0)*NPIX + n] = p0 + b_out[0];
    out[((size_t)b*3 + 1)*NPIX + n] = p1 + b_out[1];
    out[((size_t)b*3 + 2)*NPIX + n] = p2 + b_out[2];
  }
}

extern "C" void kernel_launch(void* const* d_in, const int* in_sizes, int n_in,
                              void* d_out, int out_size, void* d_ws, size_t ws_size,
                              hipStream_t stream) {
  const float* x     = (const float*)d_in[0];
  // d_in[1] = src, d_in[2] = dst — unused: grid topology is analytic
  const float* W_in  = (const float*)d_in[3];
  const float* b_in  = (const float*)d_in[4];
  const float* Wg    = (const float*)d_in[5];
  const float* bg    = (const float*)d_in[6];
  const float* W_out = (const float*)d_in[7];
  const float* b_out = (const float*)d_in[8];
  float* out = (float*)d_out;

  // WgT fp16 scratch at head of d_out (R2/R8-proven: k_out fully overwrites later)
  __half* WgT = (__half*)d_out;
  __half* hA = (__half*)d_ws;
  __half* hB = hA + (size_t)BATCH*NPIX*HID;

  k_wg<<<dim3(48), 256, 0, stream>>>(Wg, WgT);

  dim3 lg(W_IMG/TX, H_IMG/TY, BATCH);   // 32 x 32 x 4 = 4096 blocks
  k_layer<0><<<lg, LTH, 0, stream>>>(x, W_in, b_in, nullptr, WgT,        bg,       hA);
  k_layer<1><<<lg, LTH, 0, stream>>>(nullptr, nullptr, nullptr, hA, WgT + 4096, bg + 64,  hB);
  k_layer<1><<<lg, LTH, 0, stream>>>(nullptr, nullptr, nullptr, hB, WgT + 8192, bg + 128, hA);

  k_out<<<dim3(BATCH*NPIX*8/256), 256, 0, stream>>>(hA, W_out, b_out, out);
}

// Round 15
// 150.374 us; speedup vs baseline: 1.9636x; 1.0000x over previous
//
#include <hip/hip_runtime.h>
#include <hip/hip_fp16.h>

#define H_IMG 256
#define W_IMG 512
#define NPIX  (H_IMG*W_IMG)   // 131072
#define BATCH 4
#define HID   64

#define TX 16
#define TY 8
#define HX (TX+2)   // 18
#define HY (TY+2)   // 10
#define HN (HX*HY)  // 180
#define TN (TX*TY)  // 128 output nodes per tile
#define LTH 256

// Two 16x8 tiles per block (adjacent in x), each with its own 23 KB halo
// buffer. All async loads for BOTH buffers issue before ONE drain -> 2x
// memory-level parallelism during staging; GEMM(t0) overlaps stencil(t1)
// barrier-free (disjoint buffers).
// LDS layout per buffer: node-major, 64 halfs/node, XOR-swizzled chunks
// (chunk c8 of node n at n*64 + ((c8^(n&7))*8)); global source pre-swizzled.

typedef _Float16 half8 __attribute__((ext_vector_type(8)));
typedef float v4f __attribute__((ext_vector_type(4)));

#define GLOAD16(gp, lp) \
  __builtin_amdgcn_global_load_lds((const __attribute__((address_space(1))) unsigned int*)(gp), \
                                   (__attribute__((address_space(3))) unsigned int*)(lp), 16, 0, 0)

__device__ __forceinline__ float dinvf(int y, int x) {
  int cy = 3 - (y==0) - (y==(H_IMG-1));
  int cx = 3 - (x==0) - (x==(W_IMG-1));
  return rsqrtf((float)(cy*cx));
}

__device__ __forceinline__ unsigned pack2(float a, float b) {
  __half2 h = __floats2half2_rn(a, b);
  return *reinterpret_cast<unsigned*>(&h);
}

// WgT[l][f][k] = fp16(Wg[l][k][f])   (R2/R8-proven)
__global__ void k_wg(const float* __restrict__ Wg, __half* __restrict__ WgT) {
  int idx = blockIdx.x * 256 + threadIdx.x;          // 3*64*64 = 12288
  int l = idx >> 12, rem = idx & 4095;
  int f = rem >> 6, k = rem & 63;
  WgT[idx] = __float2half(Wg[(l << 12) + (k << 6) + f]);
}

// One GCN layer. MODE 0: build h0 from x on the fly; MODE 1: async-stage from hin.
template<int MODE>
__global__ __launch_bounds__(LTH, 4) void k_layer(
    const float* __restrict__ x,
    const float* __restrict__ W_in, const float* __restrict__ b_in,
    const __half* __restrict__ hin, const __half* __restrict__ wgt,
    const float* __restrict__ bg, __half* __restrict__ hout) {
  __shared__ __half hs[2][HN * 64];   // 46,080 B -> 3 blocks/CU
  const int tid = threadIdx.x;
  const int bx0 = blockIdx.x * (2*TX);
  const int ty0 = blockIdx.y * TY;
  const int b   = blockIdx.z;

  const int l64 = tid & 63, lm = l64 & 15, lh = l64 >> 4, w = tid >> 6;

  // A fragments (WgT, fp16) + bias C-input (R8-proven)
  half8 af0[4], af1[4];
  v4f cb[4];
#pragma unroll
  for (int ft = 0; ft < 4; ++ft) {
    const __half* wp = wgt + (ft*16 + lm)*64 + lh*8;
    af0[ft] = *(const half8*)wp;
    af1[ft] = *(const half8*)(wp + 32);
    cb[ft] = *(const v4f*)(bg + ft*16 + (lh << 2));
  }

  // ---- stage BOTH tiles before the single drain ----
  if (MODE == 0) {
    // h0 halos built on the fly from x; swizzled ds-writes; OOB -> 0
    const float* xb = x + (size_t)b*3*NPIX;
#pragma unroll
    for (int t = 0; t < 2; ++t) {
      const int tx0 = bx0 + t*TX;
      for (int n = tid; n < HN; n += LTH) {
        int row = n / HX, col = n - row*HX;
        int gy = ty0 - 1 + row, gx = tx0 - 1 + col;
        __half* hp = &hs[t][n << 6];
        const int s7 = n & 7;
        if ((unsigned)gy < H_IMG && (unsigned)gx < W_IMG) {
          int gi = (gy << 9) + gx;
          float x0 = xb[gi], x1 = xb[NPIX+gi], x2 = xb[2*NPIX+gi];
#pragma unroll
          for (int c8 = 0; c8 < 8; ++c8) {
            float rr[8];
#pragma unroll
            for (int k = 0; k < 8; ++k) {
              int f = (c8 << 3) + k;
              rr[k] = fmaf(x0, W_in[f], fmaf(x1, W_in[64+f], fmaf(x2, W_in[128+f], b_in[f])));
            }
            uint4 u = make_uint4(pack2(rr[0],rr[1]), pack2(rr[2],rr[3]),
                                 pack2(rr[4],rr[5]), pack2(rr[6],rr[7]));
            *(uint4*)(hp + ((c8 ^ s7) << 3)) = u;
          }
        } else {
          uint4 z = make_uint4(0u,0u,0u,0u);
#pragma unroll
          for (int c8 = 0; c8 < 8; ++c8)
            *(uint4*)(hp + ((c8 ^ s7) << 3)) = z;
        }
      }
    }
  } else {
    // async staging: all 2x1440 16B global_load_lds issued back-to-back;
    // clamped addrs, OOB handled by zeroed stencil scales. (R11-proven)
    const __half* hb = hin + (size_t)b * NPIX * HID;
#pragma unroll
    for (int t = 0; t < 2; ++t) {
      const int tx0 = bx0 + t*TX;
      for (int it = tid; it < HN*8; it += LTH) {
        int nl = it >> 3;
        int c8s = (it & 7) ^ (nl & 7);
        int row = nl / HX, col = nl - row*HX;
        int sy = ty0 - 1 + row, sx = tx0 - 1 + col;
        sy = max(0, min(H_IMG-1, sy));
        sx = max(0, min(W_IMG-1, sx));
        const __half* gp = hb + ((size_t)((sy << 9) + sx)) * 64 + (c8s << 3);
        GLOAD16(gp, &hs[t][it << 3]);
      }
    }
  }
  __syncthreads();   // ONE drain for both buffers (2x in-flight during fill)

  __half* ho = hout + (size_t)b * NPIX * HID;

  // ---- two tiles sequentially; GEMM(t0) overlaps stencil(t1) barrier-free ----
#pragma unroll
  for (int t = 0; t < 2; ++t) {
    const int tx0 = bx0 + t*TX;

    // 9-point stencil, fp32 acc; 2 threads/node x 4 octets (R14-proven)
    const int nn0 = tid & (TN-1);       // node: row nn0>>4, col nn0&15
    const int c4  = tid >> 7;           // 0 or 1: octets c4*4 .. c4*4+3
    const int lx = nn0 & 15, ly = nn0 >> 4;
    const int gy = ty0 + ly, gx = tx0 + lx;
    const float dc = dinvf(gy, gx);
    float sc[9];
    int   nbn[9];
#pragma unroll
    for (int r = 0; r < 3; ++r)
#pragma unroll
      for (int c = 0; c < 3; ++c) {
        int ny = gy - 1 + r, nx = gx - 1 + c;
        bool ok = ((unsigned)ny < H_IMG) && ((unsigned)nx < W_IMG);
        sc[r*3+c] = ok ? dc * dinvf(ny, nx) : 0.f;
        nbn[r*3+c] = (ly + r)*HX + lx + c;   // node index in halo
      }
    half8 sreg[4];
#pragma unroll
    for (int ch4 = 0; ch4 < 4; ++ch4) {
      const int ch = (c4 << 2) + ch4;
      float acc[8] = {0.f,0.f,0.f,0.f,0.f,0.f,0.f,0.f};
#pragma unroll
      for (int j = 0; j < 9; ++j) {
        int nj = nbn[j];
        half8 v = *(const half8*)&hs[t][(nj << 6) + (((ch ^ (nj & 7))) << 3)];
        float s = sc[j];
#pragma unroll
        for (int k = 0; k < 8; ++k) acc[k] = fmaf(s, (float)v[k], acc[k]);
      }
      half8 o;
#pragma unroll
      for (int k = 0; k < 8; ++k) o[k] = (_Float16)acc[k];
      sreg[ch4] = o;
    }
    __syncthreads();                 // halo reads of buf[t] done

    // spill s (fp16) into buf[t], node nn0, swizzled chunks
    {
      __half* hp = &hs[t][nn0 << 6];
      const int s7 = nn0 & 7;
#pragma unroll
      for (int ch4 = 0; ch4 < 4; ++ch4) {
        const int ch = (c4 << 2) + ch4;
        *(half8*)(hp + ((ch ^ s7) << 3)) = sreg[ch4];
      }
    }
    __syncthreads();                 // spill visible

    // GEMM: D = WgT (64f x 64k) x s^T; 4 waves x 2 node-groups (R14-proven)
#pragma unroll
    for (int i = 0; i < 2; ++i) {
      int g  = (w << 1) + i;          // node group: 16 nodes (8 groups total)
      int nn = (g << 4) + lm;         // local node for this lane
      const int s7 = nn & 7;
      const __half* np = &hs[t][nn << 6];
      half8 b0 = *(const half8*)(np + ((lh ^ s7) << 3));
      half8 b1 = *(const half8*)(np + (((lh + 4) ^ s7) << 3));
      v4f d[4];
#pragma unroll
      for (int ft = 0; ft < 4; ++ft) {
        v4f tt = __builtin_amdgcn_mfma_f32_16x16x32_f16(af0[ft], b0, cb[ft], 0, 0, 0);
        d[ft]  = __builtin_amdgcn_mfma_f32_16x16x32_f16(af1[ft], b1, tt,    0, 0, 0);
      }
      __half* hp = ho + (size_t)(((ty0 + (nn >> 4)) << 9) + tx0 + (nn & 15)) * HID + (lh << 2);
#pragma unroll
      for (int ft = 0; ft < 4; ++ft) {
        uint2 u;
        u.x = pack2(fmaxf(d[ft][0], 0.f), fmaxf(d[ft][1], 0.f));
        u.y = pack2(fmaxf(d[ft][2], 0.f), fmaxf(d[ft][3], 0.f));
        *(uint2*)(hp + ft*16) = u;
      }
    }
    // no barrier before next tile: stencil(t+1) reads only buf[t+1] (stable)
  }
}

// out[b,c,n] = h[b,n,:] @ W_out + b_out   (R2/R8-proven)
__global__ void k_out(const __half* __restrict__ h, const float* __restrict__ W_out,
                      const float* __restrict__ b_out, float* __restrict__ out) {
  int idx = blockIdx.x * 256 + threadIdx.x;
  int c8 = idx & 7;
  int bn = idx >> 3;
  uint4 raw = *reinterpret_cast<const uint4*>(h + (size_t)bn*64 + (size_t)c8*8);
  const __half2* hp = reinterpret_cast<const __half2*>(&raw);
  float p0 = 0.f, p1 = 0.f, p2 = 0.f;
  int fbase = c8*8;
#pragma unroll
  for (int j = 0; j < 4; ++j) {
    float2 f = __half22float2(hp[j]);
    const float* wv = &W_out[(fbase + j*2)*3];
    p0 += f.x*wv[0] + f.y*wv[3];
    p1 += f.x*wv[1] + f.y*wv[4];
    p2 += f.x*wv[2] + f.y*wv[5];
  }
#pragma unroll
  for (int m = 1; m < 8; m <<= 1) {
    p0 += __shfl_xor(p0, m);
    p1 += __shfl_xor(p1, m);
    p2 += __shfl_xor(p2, m);
  }
  if (c8 == 0) {
    int b = bn >> 17, n = bn & (NPIX-1);
    out[((size_t)b*3 + 0)*NPIX + n] = p0 + b_out[0];
    out[((size_t)b*3 + 1)*NPIX + n] = p1 + b_out[1];
    out[((size_t)b*3 + 2)*NPIX + n] = p2 + b_out[2];
  }
}

extern "C" void kernel_launch(void* const* d_in, const int* in_sizes, int n_in,
                              void* d_out, int out_size, void* d_ws, size_t ws_size,
                              hipStream_t stream) {
  const float* x     = (const float*)d_in[0];
  // d_in[1] = src, d_in[2] = dst — unused: grid topology is analytic
  const float* W_in  = (const float*)d_in[3];
  const float* b_in  = (const float*)d_in[4];
  const float* Wg    = (const float*)d_in[5];
  const float* bg    = (const float*)d_in[6];
  const float* W_out = (const float*)d_in[7];
  const float* b_out = (const float*)d_in[8];
  float* out = (float*)d_out;

  // WgT fp16 scratch at head of d_out (R2/R8-proven: k_out fully overwrites later)
  __half* WgT = (__half*)d_out;
  __half* hA = (__half*)d_ws;
  __half* hB = hA + (size_t)BATCH*NPIX*HID;

  k_wg<<<dim3(48), 256, 0, stream>>>(Wg, WgT);

  dim3 lg(W_IMG/(2*TX), H_IMG/TY, BATCH);   // 16 x 32 x 4 = 2048 blocks
  k_layer<0><<<lg, LTH, 0, stream>>>(x, W_in, b_in, nullptr, WgT,        bg,       hA);
  k_layer<1><<<lg, LTH, 0, stream>>>(nullptr, nullptr, nullptr, hA, WgT + 4096, bg + 64,  hB);
  k_layer<1><<<lg, LTH, 0, stream>>>(nullptr, nullptr, nullptr, hB, WgT + 8192, bg + 128, hA);

  k_out<<<dim3(BATCH*NPIX*8/256), 256, 0, stream>>>(hA, W_out, b_out, out);
}

// Round 16
// 134.650 us; speedup vs baseline: 2.1929x; 1.1168x over previous
//
#include <hip/hip_runtime.h>
#include <hip/hip_fp16.h>

#define H_IMG 256
#define W_IMG 512
#define NPIX  (H_IMG*W_IMG)   // 131072
#define BATCH 4
#define HID   64

#define TX 32
#define TY 8
#define HX (TX+2)   // 34
#define HY (TY+2)   // 10
#define HN (HX*HY)  // 340
#define LTH 256

// LDS: node-major, 64 halfs (128 B) per node, NO pad (global_load_lds writes
// linearly). Bank conflicts handled by XOR swizzle: chunk c8 of node n lives
// at halfs n*64 + ((c8 ^ (n&7))*8). Staging pre-swizzles the GLOBAL source
// chunk so the linear LDS write lands swizzled (rule: both-sides-or-neither).

typedef _Float16 half8 __attribute__((ext_vector_type(8)));
typedef float v4f __attribute__((ext_vector_type(4)));

#define GLOAD16(gp, lp) \
  __builtin_amdgcn_global_load_lds((const __attribute__((address_space(1))) unsigned int*)(gp), \
                                   (__attribute__((address_space(3))) unsigned int*)(lp), 16, 0, 0)

__device__ __forceinline__ float dinvf(int y, int x) {
  int cy = 3 - (y==0) - (y==(H_IMG-1));
  int cx = 3 - (x==0) - (x==(W_IMG-1));
  return rsqrtf((float)(cy*cx));
}

__device__ __forceinline__ unsigned pack2(float a, float b) {
  __half2 h = __floats2half2_rn(a, b);
  return *reinterpret_cast<unsigned*>(&h);
}

// acc{L,H} += fp16{lo,hi}(hv) * s   — forced v_fma_mix_f32 (no cvt insts).
// Arithmetic identical to fmaf((float)h16, s, acc).
__device__ __forceinline__ void fma_mix2(float& accL, float& accH, unsigned hv, float s) {
  asm("v_fma_mix_f32 %0, %2, %3, %0 op_sel:[0,0,0] op_sel_hi:[1,0,0]\n\t"
      "v_fma_mix_f32 %1, %2, %3, %1 op_sel:[1,0,0] op_sel_hi:[1,0,0]"
      : "+v"(accL), "+v"(accH)
      : "v"(hv), "v"(s));
}

// WgT[l][f][k] = fp16(Wg[l][k][f])   (R2/R8-proven)
__global__ void k_wg(const float* __restrict__ Wg, __half* __restrict__ WgT) {
  int idx = blockIdx.x * 256 + threadIdx.x;          // 3*64*64 = 12288
  int l = idx >> 12, rem = idx & 4095;
  int f = rem >> 6, k = rem & 63;
  WgT[idx] = __float2half(Wg[(l << 12) + (k << 6) + f]);
}

// One GCN layer (R11 base: 32x8 tile, 256 threads, 1 node/thread, 8 octets).
// MODE 0: build h0 from x on the fly; MODE 1: async-stage from hin.
template<int MODE>
__global__ __launch_bounds__(LTH, 3) void k_layer(
    const float* __restrict__ x,
    const float* __restrict__ W_in, const float* __restrict__ b_in,
    const __half* __restrict__ hin, const __half* __restrict__ wgt,
    const float* __restrict__ bg, __half* __restrict__ hout) {
  __shared__ __half hs[HN * 64];   // 43,520 B -> 3 blocks/CU
  const int tid = threadIdx.x;
  const int tx0 = blockIdx.x * TX;
  const int ty0 = blockIdx.y * TY;
  const int b   = blockIdx.z;

  const int l64 = tid & 63, lm = l64 & 15, lh = l64 >> 4, w = tid >> 6;

  // A fragments (WgT, fp16) + bias C-input (R8-proven)
  half8 af0[4], af1[4];
  v4f cb[4];
#pragma unroll
  for (int ft = 0; ft < 4; ++ft) {
    const __half* wp = wgt + (ft*16 + lm)*64 + lh*8;
    af0[ft] = *(const half8*)wp;
    af1[ft] = *(const half8*)(wp + 32);
    cb[ft] = *(const v4f*)(bg + ft*16 + (lh << 2));
  }

  // ---- staging ----
  if (MODE == 0) {
    // h0 halo built on the fly from x; swizzled ds-writes; OOB -> 0
    const float* xb = x + (size_t)b*3*NPIX;
    for (int n = tid; n < HN; n += LTH) {
      int row = n / HX, col = n - row*HX;
      int gy = ty0 - 1 + row, gx = tx0 - 1 + col;
      __half* hp = &hs[n << 6];
      const int s7 = n & 7;
      if ((unsigned)gy < H_IMG && (unsigned)gx < W_IMG) {
        int gi = (gy << 9) + gx;
        float x0 = xb[gi], x1 = xb[NPIX+gi], x2 = xb[2*NPIX+gi];
#pragma unroll
        for (int c8 = 0; c8 < 8; ++c8) {
          float rr[8];
#pragma unroll
          for (int k = 0; k < 8; ++k) {
            int f = (c8 << 3) + k;
            rr[k] = fmaf(x0, W_in[f], fmaf(x1, W_in[64+f], fmaf(x2, W_in[128+f], b_in[f])));
          }
          uint4 u = make_uint4(pack2(rr[0],rr[1]), pack2(rr[2],rr[3]),
                               pack2(rr[4],rr[5]), pack2(rr[6],rr[7]));
          *(uint4*)(hp + ((c8 ^ s7) << 3)) = u;
        }
      } else {
        uint4 z = make_uint4(0u,0u,0u,0u);
#pragma unroll
        for (int c8 = 0; c8 < 8; ++c8)
          *(uint4*)(hp + ((c8 ^ s7) << 3)) = z;
      }
    }
  } else {
    // async staging: back-to-back global_load_lds (16B); clamped addrs,
    // OOB handled by zeroed stencil scales. (R11-proven)
    const __half* hb = hin + (size_t)b * NPIX * HID;
    for (int it = tid; it < HN*8; it += LTH) {
      int nl = it >> 3;
      int c8s = (it & 7) ^ (nl & 7);
      int row = nl / HX, col = nl - row*HX;
      int sy = ty0 - 1 + row, sx = tx0 - 1 + col;
      sy = max(0, min(H_IMG-1, sy));
      sx = max(0, min(W_IMG-1, sx));
      const __half* gp = hb + ((size_t)((sy << 9) + sx)) * 64 + (c8s << 3);
      GLOAD16(gp, &hs[it << 3]);
    }
  }
  __syncthreads();   // compiler drains vmcnt before barrier

  // ---- 9-point stencil, fp32 acc via forced v_fma_mix_f32 ----
  const int lx = tid & 31, ly = tid >> 5;
  const int gy = ty0 + ly, gx = tx0 + lx;
  const float dc = dinvf(gy, gx);
  float sc[9];
  int   nbn[9];
#pragma unroll
  for (int r = 0; r < 3; ++r)
#pragma unroll
    for (int c = 0; c < 3; ++c) {
      int ny = gy - 1 + r, nx = gx - 1 + c;
      bool ok = ((unsigned)ny < H_IMG) && ((unsigned)nx < W_IMG);
      sc[r*3+c] = ok ? dc * dinvf(ny, nx) : 0.f;
      nbn[r*3+c] = (ly + r)*HX + lx + c;   // node index in halo
    }
  half8 sreg[8];
#pragma unroll
  for (int ch = 0; ch < 8; ++ch) {
    float acc[8] = {0.f,0.f,0.f,0.f,0.f,0.f,0.f,0.f};
#pragma unroll
    for (int j = 0; j < 9; ++j) {
      int nj = nbn[j];
      uint4 v = *(const uint4*)&hs[(nj << 6) + (((ch ^ (nj & 7))) << 3)];
      float s = sc[j];
      fma_mix2(acc[0], acc[1], v.x, s);
      fma_mix2(acc[2], acc[3], v.y, s);
      fma_mix2(acc[4], acc[5], v.z, s);
      fma_mix2(acc[6], acc[7], v.w, s);
    }
    half8 o;
#pragma unroll
    for (int k = 0; k < 8; ++k) o[k] = (_Float16)acc[k];
    sreg[ch] = o;
  }
  __syncthreads();                 // all halo reads done; safe to overwrite

  // spill s (fp16) into LDS, node = tid, swizzled chunks
  {
    __half* hp = &hs[tid << 6];
    const int s7 = tid & 7;
#pragma unroll
    for (int ch = 0; ch < 8; ++ch)
      *(half8*)(hp + ((ch ^ s7) << 3)) = sreg[ch];
  }
  __syncthreads();

  // ---- GEMM: D = WgT (64f x 64k) x s^T; D[f][node]; swizzled b-frag reads ----
  __half* ho = hout + (size_t)b * NPIX * HID;
#pragma unroll
  for (int i = 0; i < 4; ++i) {
    int g  = (w << 2) + i;          // node group: 16 nodes
    int nn = (g << 4) + lm;         // local node for this lane (= tid ordering)
    const int s7 = nn & 7;
    const __half* np = &hs[nn << 6];
    half8 b0 = *(const half8*)(np + ((lh ^ s7) << 3));
    half8 b1 = *(const half8*)(np + (((lh + 4) ^ s7) << 3));
    v4f d[4];
#pragma unroll
    for (int ft = 0; ft < 4; ++ft) {
      v4f t = __builtin_amdgcn_mfma_f32_16x16x32_f16(af0[ft], b0, cb[ft], 0, 0, 0);
      d[ft]  = __builtin_amdgcn_mfma_f32_16x16x32_f16(af1[ft], b1, t,     0, 0, 0);
    }
    // lane holds features ft*16 + lh*4 + r of node nn; node nn: row nn>>5, col nn&31
    __half* hp = ho + (size_t)(((ty0 + (nn >> 5)) << 9) + tx0 + (nn & 31)) * HID + (lh << 2);
#pragma unroll
    for (int ft = 0; ft < 4; ++ft) {
      uint2 u;
      u.x = pack2(fmaxf(d[ft][0], 0.f), fmaxf(d[ft][1], 0.f));
      u.y = pack2(fmaxf(d[ft][2], 0.f), fmaxf(d[ft][3], 0.f));
      *(uint2*)(hp + ft*16) = u;
    }
  }
}

// out[b,c,n] = h[b,n,:] @ W_out + b_out   (R2/R8-proven)
__global__ void k_out(const __half* __restrict__ h, const float* __restrict__ W_out,
                      const float* __restrict__ b_out, float* __restrict__ out) {
  int idx = blockIdx.x * 256 + threadIdx.x;
  int c8 = idx & 7;
  int bn = idx >> 3;
  uint4 raw = *reinterpret_cast<const uint4*>(h + (size_t)bn*64 + (size_t)c8*8);
  const __half2* hp = reinterpret_cast<const __half2*>(&raw);
  float p0 = 0.f, p1 = 0.f, p2 = 0.f;
  int fbase = c8*8;
#pragma unroll
  for (int j = 0; j < 4; ++j) {
    float2 f = __half22float2(hp[j]);
    const float* wv = &W_out[(fbase + j*2)*3];
    p0 += f.x*wv[0] + f.y*wv[3];
    p1 += f.x*wv[1] + f.y*wv[4];
    p2 += f.x*wv[2] + f.y*wv[5];
  }
#pragma unroll
  for (int m = 1; m < 8; m <<= 1) {
    p0 += __shfl_xor(p0, m);
    p1 += __shfl_xor(p1, m);
    p2 += __shfl_xor(p2, m);
  }
  if (c8 == 0) {
    int b = bn >> 17, n = bn & (NPIX-1);
    out[((size_t)b*3 + 0)*NPIX + n] = p0 + b_out[0];
    out[((size_t)b*3 + 1)*NPIX + n] = p1 + b_out[1];
    out[((size_t)b*3 + 2)*NPIX + n] = p2 + b_out[2];
  }
}

extern "C" void kernel_launch(void* const* d_in, const int* in_sizes, int n_in,
                              void* d_out, int out_size, void* d_ws, size_t ws_size,
                              hipStream_t stream) {
  const float* x     = (const float*)d_in[0];
  // d_in[1] = src, d_in[2] = dst — unused: grid topology is analytic
  const float* W_in  = (const float*)d_in[3];
  const float* b_in  = (const float*)d_in[4];
  const float* Wg    = (const float*)d_in[5];
  const float* bg    = (const float*)d_in[6];
  const float* W_out = (const float*)d_in[7];
  const float* b_out = (const float*)d_in[8];
  float* out = (float*)d_out;

  // WgT fp16 scratch at head of d_out (R2/R8-proven: k_out fully overwrites later)
  __half* WgT = (__half*)d_out;
  __half* hA = (__half*)d_ws;
  __half* hB = hA + (size_t)BATCH*NPIX*HID;

  k_wg<<<dim3(48), 256, 0, stream>>>(Wg, WgT);

  dim3 lg(W_IMG/TX, H_IMG/TY, BATCH);   // 16 x 32 x 4
  k_layer<0><<<lg, LTH, 0, stream>>>(x, W_in, b_in, nullptr, WgT,        bg,       hA);
  k_layer<1><<<lg, LTH, 0, stream>>>(nullptr, nullptr, nullptr, hA, WgT + 4096, bg + 64,  hB);
  k_layer<1><<<lg, LTH, 0, stream>>>(nullptr, nullptr, nullptr, hB, WgT + 8192, bg + 128, hA);

  k_out<<<dim3(BATCH*NPIX*8/256), 256, 0, stream>>>(hA, W_out, b_out, out);
}

// Round 17
// 112.760 us; speedup vs baseline: 2.6186x; 1.1941x over previous
//
#include <hip/hip_runtime.h>
#include <hip/hip_fp16.h>

#define H_IMG 256
#define W_IMG 512
#define NPIX  (H_IMG*W_IMG)   // 131072
#define BATCH 4
#define HID   64

#define TX 32
#define TY 8
#define HX (TX+2)   // 34
#define HY (TY+2)   // 10
#define HN (HX*HY)  // 340
#define LTH 256

// LDS: node-major, 64 halfs (128 B) per node, NO pad (global_load_lds writes
// linearly). Bank conflicts handled by XOR swizzle: chunk c8 of node n lives
// at halfs n*64 + ((c8 ^ (n&7))*8). Staging pre-swizzles the GLOBAL source
// chunk so the linear LDS write lands swizzled (rule: both-sides-or-neither).

typedef _Float16 half8 __attribute__((ext_vector_type(8)));
typedef float v4f __attribute__((ext_vector_type(4)));

#define GLOAD16(gp, lp) \
  __builtin_amdgcn_global_load_lds((const __attribute__((address_space(1))) unsigned int*)(gp), \
                                   (__attribute__((address_space(3))) unsigned int*)(lp), 16, 0, 0)

__device__ __forceinline__ float dinvf(int y, int x) {
  int cy = 3 - (y==0) - (y==(H_IMG-1));
  int cx = 3 - (x==0) - (x==(W_IMG-1));
  return rsqrtf((float)(cy*cx));
}

__device__ __forceinline__ unsigned pack2(float a, float b) {
  __half2 h = __floats2half2_rn(a, b);
  return *reinterpret_cast<unsigned*>(&h);
}

// acc{L,H} += fp16{lo,hi}(hv) * s   — forced v_fma_mix_f32 (R16-proven)
__device__ __forceinline__ void fma_mix2(float& accL, float& accH, unsigned hv, float s) {
  asm("v_fma_mix_f32 %0, %2, %3, %0 op_sel:[0,0,0] op_sel_hi:[1,0,0]\n\t"
      "v_fma_mix_f32 %1, %2, %3, %1 op_sel:[1,0,0] op_sel_hi:[1,0,0]"
      : "+v"(accL), "+v"(accH)
      : "v"(hv), "v"(s));
}

// WgT[l][f][k] = fp16(Wg[l][k][f])   (R2/R8-proven)
__global__ void k_wg(const float* __restrict__ Wg, __half* __restrict__ WgT) {
  int idx = blockIdx.x * 256 + threadIdx.x;          // 3*64*64 = 12288
  int l = idx >> 12, rem = idx & 4095;
  int f = rem >> 6, k = rem & 63;
  WgT[idx] = __float2half(Wg[(l << 12) + (k << 6) + f]);
}

// Copy layer-3 WgT slice (4096 halfs) from d_out head into dead hA region
// (layer 3 writes d_out, so it must not read weights from d_out).  (R9-validated)
__global__ void k_prep2(const __half* __restrict__ src, __half* __restrict__ dst) {
  int idx = blockIdx.x * 256 + threadIdx.x;
  if (idx < 4096) dst[idx] = src[idx];
}

// One GCN layer (R16 base: 32x8 tile, 256 threads, 1 node/thread, 8 octets).
// MODE 0: build h0 from x on the fly;  MODE 1: async-stage from hin;
// MODE 2: as MODE 1, but GEMM result -> LDS, then W_out projection -> outp
//         (no shfl, no predicated stores, W_out read from input pointer).
template<int MODE>
__global__ __launch_bounds__(LTH, 3) void k_layer(
    const float* __restrict__ x,
    const float* __restrict__ W_in, const float* __restrict__ b_in,
    const __half* __restrict__ hin, const __half* __restrict__ wgt,
    const float* __restrict__ bg, __half* __restrict__ hout,
    const float* __restrict__ W_out, const float* __restrict__ b_out,
    float* __restrict__ outp) {
  __shared__ __half hs[HN * 64];   // 43,520 B -> 3 blocks/CU
  const int tid = threadIdx.x;
  const int tx0 = blockIdx.x * TX;
  const int ty0 = blockIdx.y * TY;
  const int b   = blockIdx.z;

  const int l64 = tid & 63, lm = l64 & 15, lh = l64 >> 4, w = tid >> 6;

  // A fragments (WgT, fp16) + bias C-input (R8-proven)
  half8 af0[4], af1[4];
  v4f cb[4];
#pragma unroll
  for (int ft = 0; ft < 4; ++ft) {
    const __half* wp = wgt + (ft*16 + lm)*64 + lh*8;
    af0[ft] = *(const half8*)wp;
    af1[ft] = *(const half8*)(wp + 32);
    cb[ft] = *(const v4f*)(bg + ft*16 + (lh << 2));
  }

  // ---- staging ----
  if (MODE == 0) {
    // h0 halo built on the fly from x; swizzled ds-writes; OOB -> 0
    const float* xb = x + (size_t)b*3*NPIX;
    for (int n = tid; n < HN; n += LTH) {
      int row = n / HX, col = n - row*HX;
      int gy = ty0 - 1 + row, gx = tx0 - 1 + col;
      __half* hp = &hs[n << 6];
      const int s7 = n & 7;
      if ((unsigned)gy < H_IMG && (unsigned)gx < W_IMG) {
        int gi = (gy << 9) + gx;
        float x0 = xb[gi], x1 = xb[NPIX+gi], x2 = xb[2*NPIX+gi];
#pragma unroll
        for (int c8 = 0; c8 < 8; ++c8) {
          float rr[8];
#pragma unroll
          for (int k = 0; k < 8; ++k) {
            int f = (c8 << 3) + k;
            rr[k] = fmaf(x0, W_in[f], fmaf(x1, W_in[64+f], fmaf(x2, W_in[128+f], b_in[f])));
          }
          uint4 u = make_uint4(pack2(rr[0],rr[1]), pack2(rr[2],rr[3]),
                               pack2(rr[4],rr[5]), pack2(rr[6],rr[7]));
          *(uint4*)(hp + ((c8 ^ s7) << 3)) = u;
        }
      } else {
        uint4 z = make_uint4(0u,0u,0u,0u);
#pragma unroll
        for (int c8 = 0; c8 < 8; ++c8)
          *(uint4*)(hp + ((c8 ^ s7) << 3)) = z;
      }
    }
  } else {
    // async staging: back-to-back global_load_lds (16B); clamped addrs,
    // OOB handled by zeroed stencil scales. (R11-proven)
    const __half* hb = hin + (size_t)b * NPIX * HID;
    for (int it = tid; it < HN*8; it += LTH) {
      int nl = it >> 3;
      int c8s = (it & 7) ^ (nl & 7);
      int row = nl / HX, col = nl - row*HX;
      int sy = ty0 - 1 + row, sx = tx0 - 1 + col;
      sy = max(0, min(H_IMG-1, sy));
      sx = max(0, min(W_IMG-1, sx));
      const __half* gp = hb + ((size_t)((sy << 9) + sx)) * 64 + (c8s << 3);
      GLOAD16(gp, &hs[it << 3]);
    }
  }
  __syncthreads();   // compiler drains vmcnt before barrier

  // ---- 9-point stencil, fp32 acc via forced v_fma_mix_f32 (R16-proven) ----
  const int lx = tid & 31, ly = tid >> 5;
  const int gy = ty0 + ly, gx = tx0 + lx;
  const float dc = dinvf(gy, gx);
  float sc[9];
  int   nbn[9];
#pragma unroll
  for (int r = 0; r < 3; ++r)
#pragma unroll
    for (int c = 0; c < 3; ++c) {
      int ny = gy - 1 + r, nx = gx - 1 + c;
      bool ok = ((unsigned)ny < H_IMG) && ((unsigned)nx < W_IMG);
      sc[r*3+c] = ok ? dc * dinvf(ny, nx) : 0.f;
      nbn[r*3+c] = (ly + r)*HX + lx + c;   // node index in halo
    }
  half8 sreg[8];
#pragma unroll
  for (int ch = 0; ch < 8; ++ch) {
    float acc[8] = {0.f,0.f,0.f,0.f,0.f,0.f,0.f,0.f};
#pragma unroll
    for (int j = 0; j < 9; ++j) {
      int nj = nbn[j];
      uint4 v = *(const uint4*)&hs[(nj << 6) + (((ch ^ (nj & 7))) << 3)];
      float s = sc[j];
      fma_mix2(acc[0], acc[1], v.x, s);
      fma_mix2(acc[2], acc[3], v.y, s);
      fma_mix2(acc[4], acc[5], v.z, s);
      fma_mix2(acc[6], acc[7], v.w, s);
    }
    half8 o;
#pragma unroll
    for (int k = 0; k < 8; ++k) o[k] = (_Float16)acc[k];
    sreg[ch] = o;
  }
  __syncthreads();                 // all halo reads done; safe to overwrite

  // spill s (fp16) into LDS, node = tid, swizzled chunks (R11-proven)
  {
    __half* hp = &hs[tid << 6];
    const int s7 = tid & 7;
#pragma unroll
    for (int ch = 0; ch < 8; ++ch)
      *(half8*)(hp + ((ch ^ s7) << 3)) = sreg[ch];
  }
  __syncthreads();

  // ---- GEMM: D = WgT (64f x 64k) x s^T; D[f][node]; swizzled b-frag reads ----
  __half* ho = (MODE != 2) ? (hout + (size_t)b * NPIX * HID) : nullptr;
#pragma unroll
  for (int i = 0; i < 4; ++i) {
    int g  = (w << 2) + i;          // node group: 16 nodes
    int nn = (g << 4) + lm;         // local node for this lane (= tid ordering)
    const int s7 = nn & 7;
    const __half* np = &hs[nn << 6];
    half8 b0 = *(const half8*)(np + ((lh ^ s7) << 3));
    half8 b1 = *(const half8*)(np + (((lh + 4) ^ s7) << 3));
    v4f d[4];
#pragma unroll
    for (int ft = 0; ft < 4; ++ft) {
      v4f t = __builtin_amdgcn_mfma_f32_16x16x32_f16(af0[ft], b0, cb[ft], 0, 0, 0);
      d[ft]  = __builtin_amdgcn_mfma_f32_16x16x32_f16(af1[ft], b1, t,     0, 0, 0);
    }
    if (MODE != 2) {
      // lane holds features ft*16 + lh*4 + r of node nn; row nn>>5, col nn&31
      __half* hp = ho + (size_t)(((ty0 + (nn >> 5)) << 9) + tx0 + (nn & 31)) * HID + (lh << 2);
#pragma unroll
      for (int ft = 0; ft < 4; ++ft) {
        uint2 u;
        u.x = pack2(fmaxf(d[ft][0], 0.f), fmaxf(d[ft][1], 0.f));
        u.y = pack2(fmaxf(d[ft][2], 0.f), fmaxf(d[ft][3], 0.f));
        *(uint2*)(hp + ft*16) = u;
      }
    } else {
      // relu(h3) -> LDS (same swizzled layout; this wave's nodes only ->
      // program order protects read-before-write; no other wave touches them)
      __half* hp = &hs[nn << 6];
#pragma unroll
      for (int ft = 0; ft < 4; ++ft) {
        int pos = ft*16 + (lh << 2);          // half index within node
        int c8 = pos >> 3, sub = pos & 7;
        uint2 u;
        u.x = pack2(fmaxf(d[ft][0], 0.f), fmaxf(d[ft][1], 0.f));
        u.y = pack2(fmaxf(d[ft][2], 0.f), fmaxf(d[ft][3], 0.f));
        *(uint2*)(hp + ((c8 ^ s7) << 3) + sub) = u;
      }
    }
  }

  // ---- MODE 2 epilogue: out = h3 @ W_out + b_out, LDS-sourced, k_out-style ----
  if (MODE == 2) {
    __syncthreads();               // h3 spill visible to all
    const int prow = tid >> 5, pcol = tid & 31;
    const int pgi = ((ty0 + prow) << 9) + tx0 + pcol;
    const __half* hp = &hs[tid << 6];
    const int s7p = tid & 7;
    float p0 = b_out[0], p1 = b_out[1], p2 = b_out[2];
#pragma unroll
    for (int o = 0; o < 8; ++o) {
      half8 v = *(const half8*)(hp + ((o ^ s7p) << 3));
#pragma unroll
      for (int e = 0; e < 8; ++e) {
        const float* wr = W_out + (o*8 + e)*3;   // uniform -> s_load
        float fv = (float)v[e];
        p0 = fmaf(fv, wr[0], p0);
        p1 = fmaf(fv, wr[1], p1);
        p2 = fmaf(fv, wr[2], p2);
      }
    }
    float* ob = outp + (size_t)b*3*NPIX;
    ob[pgi] = p0; ob[NPIX + pgi] = p1; ob[2*NPIX + pgi] = p2;
  }
}

extern "C" void kernel_launch(void* const* d_in, const int* in_sizes, int n_in,
                              void* d_out, int out_size, void* d_ws, size_t ws_size,
                              hipStream_t stream) {
  const float* x     = (const float*)d_in[0];
  // d_in[1] = src, d_in[2] = dst — unused: grid topology is analytic
  const float* W_in  = (const float*)d_in[3];
  const float* b_in  = (const float*)d_in[4];
  const float* Wg    = (const float*)d_in[5];
  const float* bg    = (const float*)d_in[6];
  const float* W_out = (const float*)d_in[7];
  const float* b_out = (const float*)d_in[8];
  float* out = (float*)d_out;

  // WgT fp16 scratch at head of d_out; layers 1-2 read it (stream-ordered,
  // before layer 3 overwrites d_out). Layer-3's slice is copied into hA
  // (dead after layer 2 consumed it) so layer 3 never reads d_out.
  __half* WgT = (__half*)d_out;
  __half* hA = (__half*)d_ws;
  __half* hB = hA + (size_t)BATCH*NPIX*HID;
  __half* w2c = hA;                  // layer-3 weights, in dead hA

  k_wg<<<dim3(48), 256, 0, stream>>>(Wg, WgT);

  dim3 lg(W_IMG/TX, H_IMG/TY, BATCH);   // 16 x 32 x 4
  k_layer<0><<<lg, LTH, 0, stream>>>(x, W_in, b_in, nullptr, WgT, bg, hA,
                                     nullptr, nullptr, nullptr);
  k_layer<1><<<lg, LTH, 0, stream>>>(nullptr, nullptr, nullptr, hA, WgT + 4096, bg + 64, hB,
                                     nullptr, nullptr, nullptr);
  k_prep2<<<dim3(16), 256, 0, stream>>>(WgT + 8192, w2c);
  k_layer<2><<<lg, LTH, 0, stream>>>(nullptr, nullptr, nullptr, hB, w2c, bg + 128, nullptr,
                                     W_out, b_out, out);
}

// Round 18
// 104.146 us; speedup vs baseline: 2.8352x; 1.0827x over previous
//
#include <hip/hip_runtime.h>
#include <hip/hip_fp16.h>

#define H_IMG 256
#define W_IMG 512
#define NPIX  (H_IMG*W_IMG)   // 131072
#define BATCH 4
#define HID   64

#define TX 32
#define TY 8
#define HX (TX+2)   // 34
#define HY (TY+2)   // 10
#define HN (HX*HY)  // 340
#define LTH 256

// LDS: node-major, 64 halfs (128 B) per node, NO pad (global_load_lds writes
// linearly). Bank conflicts handled by XOR swizzle: chunk c8 of node n lives
// at halfs n*64 + ((c8 ^ (n&7))*8). Staging pre-swizzles the GLOBAL source
// chunk so the linear LDS write lands swizzled (rule: both-sides-or-neither).

typedef _Float16 half8 __attribute__((ext_vector_type(8)));
typedef float v4f __attribute__((ext_vector_type(4)));

#define GLOAD16(gp, lp) \
  __builtin_amdgcn_global_load_lds((const __attribute__((address_space(1))) unsigned int*)(gp), \
                                   (__attribute__((address_space(3))) unsigned int*)(lp), 16, 0, 0)

__device__ __forceinline__ float rs1(int v, int n) {
  return rsqrtf((float)(3 - (v==0) - (v==(n-1))));   // finite for any v
}
__device__ __forceinline__ float dinvf(int y, int x) {
  int cy = 3 - (y==0) - (y==(H_IMG-1));
  int cx = 3 - (x==0) - (x==(W_IMG-1));
  return rsqrtf((float)(cy*cx));
}

__device__ __forceinline__ unsigned pack2(float a, float b) {
  __half2 h = __floats2half2_rn(a, b);
  return *reinterpret_cast<unsigned*>(&h);
}

// acc{L,H} += fp16{lo,hi}(hv) * s   — forced v_fma_mix_f32 (R16-proven)
__device__ __forceinline__ void fma_mix2(float& accL, float& accH, unsigned hv, float s) {
  asm("v_fma_mix_f32 %0, %2, %3, %0 op_sel:[0,0,0] op_sel_hi:[1,0,0]\n\t"
      "v_fma_mix_f32 %1, %2, %3, %1 op_sel:[1,0,0] op_sel_hi:[1,0,0]"
      : "+v"(accL), "+v"(accH)
      : "v"(hv), "v"(s));
}

// WgT[l][f][k] = fp16(Wg[l][k][f])   (R2/R8-proven)
__global__ void k_wg(const float* __restrict__ Wg, __half* __restrict__ WgT) {
  int idx = blockIdx.x * 256 + threadIdx.x;          // 3*64*64 = 12288
  int l = idx >> 12, rem = idx & 4095;
  int f = rem >> 6, k = rem & 63;
  WgT[idx] = __float2half(Wg[(l << 12) + (k << 6) + f]);
}

// Copy layer-3 WgT slice (4096 halfs) from d_out head into dead hA region
// (layer 3 writes d_out, so it must not read weights from d_out).  (R17-proven)
__global__ void k_prep2(const __half* __restrict__ src, __half* __restrict__ dst) {
  int idx = blockIdx.x * 256 + threadIdx.x;
  if (idx < 4096) dst[idx] = src[idx];
}

// One GCN layer (32x8 tile, 256 threads).
// MODE 0: build h0 from x on the fly; FUSED stencil+GEMM (1 barrier)
// MODE 1: async-stage from hin;       FUSED stencil+GEMM (1 barrier)
// MODE 2: async-stage from hin; R17-proven multi-phase body + W_out epilogue
template<int MODE>
__global__ __launch_bounds__(LTH, 3) void k_layer(
    const float* __restrict__ x,
    const float* __restrict__ W_in, const float* __restrict__ b_in,
    const __half* __restrict__ hin, const __half* __restrict__ wgt,
    const float* __restrict__ bg, __half* __restrict__ hout,
    const float* __restrict__ W_out, const float* __restrict__ b_out,
    float* __restrict__ outp) {
  __shared__ __half hs[HN * 64];   // 43,520 B -> 3 blocks/CU
  const int tid = threadIdx.x;
  const int tx0 = blockIdx.x * TX;
  const int ty0 = blockIdx.y * TY;
  const int b   = blockIdx.z;

  const int l64 = tid & 63, lm = l64 & 15, lh = l64 >> 4, w = tid >> 6;

  // A fragments (WgT, fp16) + bias C-input (R8-proven)
  half8 af0[4], af1[4];
  v4f cb[4];
#pragma unroll
  for (int ft = 0; ft < 4; ++ft) {
    const __half* wp = wgt + (ft*16 + lm)*64 + lh*8;
    af0[ft] = *(const half8*)wp;
    af1[ft] = *(const half8*)(wp + 32);
    cb[ft] = *(const v4f*)(bg + ft*16 + (lh << 2));
  }

  // ---- staging ----
  if (MODE == 0) {
    // h0 halo built on the fly from x; swizzled ds-writes; OOB -> 0
    const float* xb = x + (size_t)b*3*NPIX;
    for (int n = tid; n < HN; n += LTH) {
      int row = n / HX, col = n - row*HX;
      int gy = ty0 - 1 + row, gx = tx0 - 1 + col;
      __half* hp = &hs[n << 6];
      const int s7 = n & 7;
      if ((unsigned)gy < H_IMG && (unsigned)gx < W_IMG) {
        int gi = (gy << 9) + gx;
        float x0 = xb[gi], x1 = xb[NPIX+gi], x2 = xb[2*NPIX+gi];
#pragma unroll
        for (int c8 = 0; c8 < 8; ++c8) {
          float rr[8];
#pragma unroll
          for (int k = 0; k < 8; ++k) {
            int f = (c8 << 3) + k;
            rr[k] = fmaf(x0, W_in[f], fmaf(x1, W_in[64+f], fmaf(x2, W_in[128+f], b_in[f])));
          }
          uint4 u = make_uint4(pack2(rr[0],rr[1]), pack2(rr[2],rr[3]),
                               pack2(rr[4],rr[5]), pack2(rr[6],rr[7]));
          *(uint4*)(hp + ((c8 ^ s7) << 3)) = u;
        }
      } else {
        uint4 z = make_uint4(0u,0u,0u,0u);
#pragma unroll
        for (int c8 = 0; c8 < 8; ++c8)
          *(uint4*)(hp + ((c8 ^ s7) << 3)) = z;
      }
    }
  } else {
    // async staging: back-to-back global_load_lds (16B); clamped addrs,
    // OOB handled by zeroed stencil scales. (R11-proven)
    const __half* hb = hin + (size_t)b * NPIX * HID;
    for (int it = tid; it < HN*8; it += LTH) {
      int nl = it >> 3;
      int c8s = (it & 7) ^ (nl & 7);
      int row = nl / HX, col = nl - row*HX;
      int sy = ty0 - 1 + row, sx = tx0 - 1 + col;
      sy = max(0, min(H_IMG-1, sy));
      sx = max(0, min(W_IMG-1, sx));
      const __half* gp = hb + ((size_t)((sy << 9) + sx)) * 64 + (c8s << 3);
      GLOAD16(gp, &hs[it << 3]);
    }
  }
  __syncthreads();   // compiler drains vmcnt before barrier

  if (MODE != 2) {
    // ================= FUSED stencil + GEMM (single-barrier layer) =========
    // Lane computes stencil s for node nn=(g*16+lm), octets lh & lh+4 —
    // exactly its MFMA B-fragment — straight from the halo. No s-spill, no
    // barriers; stencil VALU of group i+1 overlaps MFMA of group i.
    __half* ho = hout + (size_t)b * NPIX * HID;
#pragma unroll
    for (int i = 0; i < 4; ++i) {
      const int g  = (w << 2) + i;       // node group: 16 nodes
      const int nn = (g << 4) + lm;      // this lane's node
      const int r = nn >> 5, c = nn & 31;
      const int gy = ty0 + r, gx = tx0 + c;
      float ry[3] = {rs1(gy-1,H_IMG), rs1(gy,H_IMG), rs1(gy+1,H_IMG)};
      float rx[3] = {rs1(gx-1,W_IMG), rs1(gx,W_IMG), rs1(gx+1,W_IMG)};
      const float dcc = ry[1]*rx[1];
      float a0[8] = {0,0,0,0,0,0,0,0};   // octet lh   (features lh*8+e)
      float a1[8] = {0,0,0,0,0,0,0,0};   // octet lh+4 (features 32+lh*8+e)
#pragma unroll
      for (int dr = 0; dr < 3; ++dr) {
#pragma unroll
        for (int dx = 0; dx < 3; ++dx) {
          int ny = gy - 1 + dr, nx = gx - 1 + dx;
          bool ok = ((unsigned)ny < H_IMG) && ((unsigned)nx < W_IMG);
          float s = ok ? dcc * ry[dr] * rx[dx] : 0.f;
          int nj = (r + dr)*HX + (c + dx);
          const __half* base = &hs[nj << 6];
          uint4 va = *(const uint4*)(base + ((lh ^ (nj & 7)) << 3));
          uint4 vb = *(const uint4*)(base + (((lh + 4) ^ (nj & 7)) << 3));
          fma_mix2(a0[0], a0[1], va.x, s);
          fma_mix2(a0[2], a0[3], va.y, s);
          fma_mix2(a0[4], a0[5], va.z, s);
          fma_mix2(a0[6], a0[7], va.w, s);
          fma_mix2(a1[0], a1[1], vb.x, s);
          fma_mix2(a1[2], a1[3], vb.y, s);
          fma_mix2(a1[4], a1[5], vb.z, s);
          fma_mix2(a1[6], a1[7], vb.w, s);
        }
      }
      half8 b0, b1;
#pragma unroll
      for (int k = 0; k < 8; ++k) { b0[k] = (_Float16)a0[k]; b1[k] = (_Float16)a1[k]; }
      v4f d[4];
#pragma unroll
      for (int ft = 0; ft < 4; ++ft) {
        v4f t = __builtin_amdgcn_mfma_f32_16x16x32_f16(af0[ft], b0, cb[ft], 0, 0, 0);
        d[ft]  = __builtin_amdgcn_mfma_f32_16x16x32_f16(af1[ft], b1, t,     0, 0, 0);
      }
      // lane holds features ft*16 + lh*4 + e of node nn
      __half* hp = ho + (size_t)(((ty0 + r) << 9) + tx0 + c) * HID + (lh << 2);
#pragma unroll
      for (int ft = 0; ft < 4; ++ft) {
        uint2 u;
        u.x = pack2(fmaxf(d[ft][0], 0.f), fmaxf(d[ft][1], 0.f));
        u.y = pack2(fmaxf(d[ft][2], 0.f), fmaxf(d[ft][3], 0.f));
        *(uint2*)(hp + ft*16) = u;
      }
    }
    return;
  }

  // ================= MODE 2: R17-proven multi-phase body =================
  {
    const int lx = tid & 31, ly = tid >> 5;
    const int gy = ty0 + ly, gx = tx0 + lx;
    const float dc = dinvf(gy, gx);
    float sc[9];
    int   nbn[9];
#pragma unroll
    for (int r = 0; r < 3; ++r)
#pragma unroll
      for (int c = 0; c < 3; ++c) {
        int ny = gy - 1 + r, nx = gx - 1 + c;
        bool ok = ((unsigned)ny < H_IMG) && ((unsigned)nx < W_IMG);
        sc[r*3+c] = ok ? dc * dinvf(ny, nx) : 0.f;
        nbn[r*3+c] = (ly + r)*HX + lx + c;
      }
    half8 sreg[8];
#pragma unroll
    for (int ch = 0; ch < 8; ++ch) {
      float acc[8] = {0.f,0.f,0.f,0.f,0.f,0.f,0.f,0.f};
#pragma unroll
      for (int j = 0; j < 9; ++j) {
        int nj = nbn[j];
        uint4 v = *(const uint4*)&hs[(nj << 6) + (((ch ^ (nj & 7))) << 3)];
        float s = sc[j];
        fma_mix2(acc[0], acc[1], v.x, s);
        fma_mix2(acc[2], acc[3], v.y, s);
        fma_mix2(acc[4], acc[5], v.z, s);
        fma_mix2(acc[6], acc[7], v.w, s);
      }
      half8 o;
#pragma unroll
      for (int k = 0; k < 8; ++k) o[k] = (_Float16)acc[k];
      sreg[ch] = o;
    }
    __syncthreads();

    {
      __half* hp = &hs[tid << 6];
      const int s7 = tid & 7;
#pragma unroll
      for (int ch = 0; ch < 8; ++ch)
        *(half8*)(hp + ((ch ^ s7) << 3)) = sreg[ch];
    }
    __syncthreads();

#pragma unroll
    for (int i = 0; i < 4; ++i) {
      int g  = (w << 2) + i;
      int nn = (g << 4) + lm;
      const int s7 = nn & 7;
      const __half* np = &hs[nn << 6];
      half8 b0 = *(const half8*)(np + ((lh ^ s7) << 3));
      half8 b1 = *(const half8*)(np + (((lh + 4) ^ s7) << 3));
      v4f d[4];
#pragma unroll
      for (int ft = 0; ft < 4; ++ft) {
        v4f t = __builtin_amdgcn_mfma_f32_16x16x32_f16(af0[ft], b0, cb[ft], 0, 0, 0);
        d[ft]  = __builtin_amdgcn_mfma_f32_16x16x32_f16(af1[ft], b1, t,     0, 0, 0);
      }
      // relu(h3) -> LDS (this wave's nodes only; program order protects RAW)
      __half* hp = &hs[nn << 6];
#pragma unroll
      for (int ft = 0; ft < 4; ++ft) {
        int pos = ft*16 + (lh << 2);
        int c8 = pos >> 3, sub = pos & 7;
        uint2 u;
        u.x = pack2(fmaxf(d[ft][0], 0.f), fmaxf(d[ft][1], 0.f));
        u.y = pack2(fmaxf(d[ft][2], 0.f), fmaxf(d[ft][3], 0.f));
        *(uint2*)(hp + ((c8 ^ s7) << 3) + sub) = u;
      }
    }

    // epilogue: out = h3 @ W_out + b_out, LDS-sourced (R17-proven)
    __syncthreads();
    const int prow = tid >> 5, pcol = tid & 31;
    const int pgi = ((ty0 + prow) << 9) + tx0 + pcol;
    const __half* hp = &hs[tid << 6];
    const int s7p = tid & 7;
    float p0 = b_out[0], p1 = b_out[1], p2 = b_out[2];
#pragma unroll
    for (int o = 0; o < 8; ++o) {
      half8 v = *(const half8*)(hp + ((o ^ s7p) << 3));
#pragma unroll
      for (int e = 0; e < 8; ++e) {
        const float* wr = W_out + (o*8 + e)*3;   // uniform -> s_load
        float fv = (float)v[e];
        p0 = fmaf(fv, wr[0], p0);
        p1 = fmaf(fv, wr[1], p1);
        p2 = fmaf(fv, wr[2], p2);
      }
    }
    float* ob = outp + (size_t)b*3*NPIX;
    ob[pgi] = p0; ob[NPIX + pgi] = p1; ob[2*NPIX + pgi] = p2;
  }
}

extern "C" void kernel_launch(void* const* d_in, const int* in_sizes, int n_in,
                              void* d_out, int out_size, void* d_ws, size_t ws_size,
                              hipStream_t stream) {
  const float* x     = (const float*)d_in[0];
  // d_in[1] = src, d_in[2] = dst — unused: grid topology is analytic
  const float* W_in  = (const float*)d_in[3];
  const float* b_in  = (const float*)d_in[4];
  const float* Wg    = (const float*)d_in[5];
  const float* bg    = (const float*)d_in[6];
  const float* W_out = (const float*)d_in[7];
  const float* b_out = (const float*)d_in[8];
  float* out = (float*)d_out;

  // WgT fp16 scratch at head of d_out; layers 1-2 read it (stream-ordered,
  // before layer 3 overwrites d_out). Layer-3's slice is copied into hA
  // (dead after layer 2 consumed it) so layer 3 never reads d_out.
  __half* WgT = (__half*)d_out;
  __half* hA = (__half*)d_ws;
  __half* hB = hA + (size_t)BATCH*NPIX*HID;
  __half* w2c = hA;                  // layer-3 weights, in dead hA

  k_wg<<<dim3(48), 256, 0, stream>>>(Wg, WgT);

  dim3 lg(W_IMG/TX, H_IMG/TY, BATCH);   // 16 x 32 x 4
  k_layer<0><<<lg, LTH, 0, stream>>>(x, W_in, b_in, nullptr, WgT, bg, hA,
                                     nullptr, nullptr, nullptr);
  k_layer<1><<<lg, LTH, 0, stream>>>(nullptr, nullptr, nullptr, hA, WgT + 4096, bg + 64, hB,
                                     nullptr, nullptr, nullptr);
  k_prep2<<<dim3(16), 256, 0, stream>>>(WgT + 8192, w2c);
  k_layer<2><<<lg, LTH, 0, stream>>>(nullptr, nullptr, nullptr, hB, w2c, bg + 128, nullptr,
                                     W_out, b_out, out);
}